// Round 2
// baseline (1522.887 us; speedup 1.0000x reference)
//
#include <hip/hip_runtime.h>
#include <hip/hip_bf16.h>

// Problem dims (fixed by setup_inputs)
#define BB 2
#define LL 4096
#define DD 1024
#define NN 16
#define RR 64
#define KK 4
#define ROWS 8   // rows (l) per proj block

// ---------------- helpers ----------------

__device__ __forceinline__ float med3f(float x, float lo, float hi) {
    return __builtin_amdgcn_fmed3f(x, lo, hi);
}

template<int CTRL>
__device__ __forceinline__ float dpp_ror(float v) {
    int r = __builtin_amdgcn_update_dpp(0, __builtin_bit_cast(int, v), CTRL, 0xf, 0xf, true);
    return __builtin_bit_cast(float, r);
}

__device__ __forceinline__ float silu_f(float z) {
    float e = __expf(-z);
    return z * __builtin_amdgcn_rcpf(1.0f + e);
}

__device__ __forceinline__ float softplus_f(float z) {
    // log(1+exp(z)) = max(z,0) + log(1+exp(-|z|))
    float e = __expf(-fabsf(z));
    return fmaxf(z, 0.0f) + __logf(1.0f + e);
}

// ---------------- prep: weight transposes ----------------
// Wdt1T[k*64+r] = W_dt1[r*1024+k]
// Wdt2T[r*1024+d] = W_dt2[d*64+r]
// WBCT[k*32+o] = o<16 ? W_B[o*1024+k] : W_C[(o-16)*1024+k]
__global__ __launch_bounds__(256) void prep_kernel(
    const float* __restrict__ Wdt1, const float* __restrict__ Wdt2,
    const float* __restrict__ WB, const float* __restrict__ WC,
    float* __restrict__ Wdt1T, float* __restrict__ Wdt2T, float* __restrict__ WBCT)
{
    int i = blockIdx.x * 256 + threadIdx.x;   // up to 65536
    if (i < 65536) {
        int k = i >> 6, r = i & 63;
        Wdt1T[i] = Wdt1[r * 1024 + k];
    }
    if (i < 65536) {
        int r = i >> 10, d = i & 1023;
        Wdt2T[i] = Wdt2[d * 64 + r];
    }
    if (i < 32768) {
        int k = i >> 5, o = i & 31;
        WBCT[i] = (o < 16) ? WB[o * 1024 + k] : WC[(o - 16) * 1024 + k];
    }
}

// ---------------- proj: conv + silu + dt/B/C projections ----------------
__global__ __launch_bounds__(256) void proj_kernel(
    const float* __restrict__ x,
    const float* __restrict__ conv_w, const float* __restrict__ conv_b,
    const float* __restrict__ Wdt1T, const float* __restrict__ Wdt2T,
    const float* __restrict__ b_dt, const float* __restrict__ WBCT,
    float2* __restrict__ xdt, float2* __restrict__ bc)
{
    __shared__ alignas(16) float xc8[1024 * ROWS];   // [d][row], 32KB
    __shared__ alignas(16) float part[2048];         // 8KB, reused A/C
    __shared__ alignas(16) float dtpre[64 * ROWS];   // [r][row], 2KB

    const int t = threadIdx.x;
    const int blk = blockIdx.x;             // 0..1023
    const int b = blk >> 9;                 // 512 blocks per batch
    const int l0 = (blk & 511) << 3;        // row base
    const float* xb = x + (size_t)b * LL * DD;

    // ---- conv + silu, 4 d's per thread, 8 rows each ----
    float xc_reg[4][ROWS];
    #pragma unroll
    for (int dd = 0; dd < 4; ++dd) {
        int d = t + dd * 256;
        float4 w4 = reinterpret_cast<const float4*>(conv_w)[d];
        float cb = conv_b[d];
        float xv[ROWS + 3];
        #pragma unroll
        for (int j = 0; j < ROWS + 3; ++j) {
            int l = l0 - 3 + j;
            xv[j] = (l >= 0) ? xb[(size_t)l * DD + d] : 0.0f;
        }
        #pragma unroll
        for (int r = 0; r < ROWS; ++r) {
            float s = cb + xv[r] * w4.x + xv[r + 1] * w4.y + xv[r + 2] * w4.z + xv[r + 3] * w4.w;
            float v = silu_f(s);
            xc_reg[dd][r] = v;
        }
        float4 lo = make_float4(xc_reg[dd][0], xc_reg[dd][1], xc_reg[dd][2], xc_reg[dd][3]);
        float4 hi = make_float4(xc_reg[dd][4], xc_reg[dd][5], xc_reg[dd][6], xc_reg[dd][7]);
        reinterpret_cast<float4*>(&xc8[d * ROWS])[0] = lo;
        reinterpret_cast<float4*>(&xc8[d * ROWS])[1] = hi;
    }
    __syncthreads();

    const float4* xr4 = reinterpret_cast<const float4*>(xc8);

    // ---- phase A: dt_pre[r] = sum_k xc[k] * Wdt1T[k][r] ----
    {
        int r = t & 63, seg = t >> 6;           // 4 segs x 256 k
        float acc[ROWS];
        #pragma unroll
        for (int q = 0; q < ROWS; ++q) acc[q] = 0.0f;
        const float* wp = Wdt1T + (size_t)(seg * 256) * 64 + r;
        int kbase = seg * 256;
        for (int i = 0; i < 256; ++i) {
            float wv = wp[(size_t)i * 64];
            float4 a = xr4[(kbase + i) * 2];
            float4 c = xr4[(kbase + i) * 2 + 1];
            acc[0] += a.x * wv; acc[1] += a.y * wv; acc[2] += a.z * wv; acc[3] += a.w * wv;
            acc[4] += c.x * wv; acc[5] += c.y * wv; acc[6] += c.z * wv; acc[7] += c.w * wv;
        }
        #pragma unroll
        for (int q = 0; q < ROWS; ++q) part[seg * 512 + r * 8 + q] = acc[q];
    }
    __syncthreads();
    {
        // reduce 4 segs -> dtpre[r*8+row]; 512 values, 256 threads x 2
        int idx = t;
        #pragma unroll
        for (int rep = 0; rep < 2; ++rep, idx += 256) {
            float s = part[idx] + part[512 + idx] + part[1024 + idx] + part[1536 + idx];
            dtpre[idx] = s;
        }
    }
    __syncthreads();

    // ---- phase B: dt[d] = softplus(sum_r dtpre[r]*Wdt2T[r][d] + b_dt[d]); write xdt ----
    const float4* dp4 = reinterpret_cast<const float4*>(dtpre);
    #pragma unroll
    for (int dd = 0; dd < 4; ++dd) {
        int d = t + dd * 256;
        float bd = b_dt[d];
        float acc[ROWS];
        #pragma unroll
        for (int q = 0; q < ROWS; ++q) acc[q] = bd;
        const float* wp = Wdt2T + d;
        for (int r = 0; r < 64; ++r) {
            float wv = wp[(size_t)r * 1024];
            float4 p0 = dp4[r * 2];
            float4 p1 = dp4[r * 2 + 1];
            acc[0] += p0.x * wv; acc[1] += p0.y * wv; acc[2] += p0.z * wv; acc[3] += p0.w * wv;
            acc[4] += p1.x * wv; acc[5] += p1.y * wv; acc[6] += p1.z * wv; acc[7] += p1.w * wv;
        }
        #pragma unroll
        for (int row = 0; row < ROWS; ++row) {
            float sp = softplus_f(acc[row]);
            xdt[(size_t)(b * LL + l0 + row) * DD + d] = make_float2(xc_reg[dd][row], sp);
        }
    }
    // part was last READ before the barrier after phase A reduce; safe to rewrite in C.

    // ---- phase C: B_ssm/C_ssm ----
    {
        int o = t & 31, seg = t >> 5;           // 8 segs x 128 k
        float acc[ROWS];
        #pragma unroll
        for (int q = 0; q < ROWS; ++q) acc[q] = 0.0f;
        const float* wp = WBCT + (size_t)(seg * 128) * 32 + o;
        int kbase = seg * 128;
        for (int i = 0; i < 128; ++i) {
            float wv = wp[(size_t)i * 32];
            float4 a = xr4[(kbase + i) * 2];
            float4 c = xr4[(kbase + i) * 2 + 1];
            acc[0] += a.x * wv; acc[1] += a.y * wv; acc[2] += a.z * wv; acc[3] += a.w * wv;
            acc[4] += c.x * wv; acc[5] += c.y * wv; acc[6] += c.z * wv; acc[7] += c.w * wv;
        }
        #pragma unroll
        for (int q = 0; q < ROWS; ++q) part[seg * 256 + o * 8 + q] = acc[q];
    }
    __syncthreads();
    if (t < 128) {
        int n = t & 15, row = t >> 4;
        float Bv = 0.0f, Cv = 0.0f;
        #pragma unroll
        for (int seg = 0; seg < 8; ++seg) {
            Bv += part[seg * 256 + n * 8 + row];
            Cv += part[seg * 256 + (n + 16) * 8 + row];
        }
        bc[(size_t)(b * LL + l0 + row) * NN + n] = make_float2(Bv, Cv);
    }
}

// ---------------- scan: sequential over L, lane = (b, d, n) ----------------
__global__ __launch_bounds__(64) void scan_kernel(
    const float2* __restrict__ xdt, const float2* __restrict__ bc,
    const float* __restrict__ A_log, const float* __restrict__ Dparam,
    float* __restrict__ y)
{
    const int w = blockIdx.x;       // 0..511
    const int b = w >> 8;
    const int dbase = (w & 255) << 2;
    const int lane = threadIdx.x;   // 0..63
    const int n = lane & 15;
    const int dl = lane >> 4;
    const int d = dbase + dl;

    const float A = -__expf(A_log[d * NN + n]);   // < 0
    const float Dp = Dparam[d];

    const float2* xp = xdt + (size_t)b * LL * DD + d;
    const float2* bp = bc + (size_t)b * LL * NN + n;
    float* yp = y + (size_t)b * LL * DD + d;

    float h = 0.0f;
    #pragma unroll 8
    for (int l = 0; l < LL; ++l) {
        float2 xz = xp[(size_t)l * DD];
        float2 bcv = bp[(size_t)l * NN];
        float xv = xz.x, dt = xz.y;                 // dt >= 0 (softplus)
        float dtA = fmaxf(dt * A, -10.0f);          // clip(dt*A, -10, 0): product <= 0 already
        float Abar = fminf(__expf(dtA), 0.999f);    // clip(exp, 0, 0.999): exp > 0
        float tt = fminf(dt, 1.0f) * bcv.x;         // clip(dt,0,1) * B
        tt = med3f(tt, -10.0f, 10.0f);              // clip B_bar
        h = fmaf(Abar, h, tt * xv);
        h = med3f(h, -100.0f, 100.0f);
        float p = h * bcv.y;
        // sum over the 16 n-lanes via DPP row rotations (stays within 16-lane row)
        p += dpp_ror<0x121>(p);   // row_ror:1
        p += dpp_ror<0x122>(p);   // row_ror:2
        p += dpp_ror<0x124>(p);   // row_ror:4
        p += dpp_ror<0x128>(p);   // row_ror:8
        if (n == 0) {
            float yv = fmaf(Dp, xv, p);
            yp[(size_t)l * DD] = med3f(yv, -50.0f, 50.0f);
        }
    }
}

// ---------------- launch ----------------
extern "C" void kernel_launch(void* const* d_in, const int* in_sizes, int n_in,
                              void* d_out, int out_size, void* d_ws, size_t ws_size,
                              hipStream_t stream) {
    const float* x      = (const float*)d_in[0];
    const float* A_log  = (const float*)d_in[1];
    const float* Dparam = (const float*)d_in[2];
    const float* W_dt1  = (const float*)d_in[3];
    const float* W_dt2  = (const float*)d_in[4];
    const float* b_dt   = (const float*)d_in[5];
    const float* W_B    = (const float*)d_in[6];
    const float* W_C    = (const float*)d_in[7];
    const float* conv_w = (const float*)d_in[8];
    const float* conv_b = (const float*)d_in[9];
    float* y = (float*)d_out;

    float* ws = (float*)d_ws;
    // layout (floats): xdt 16M | bc 256K | Wdt1T 64K | Wdt2T 64K | WBCT 32K
    float2* xdt  = (float2*)ws;
    float2* bc   = (float2*)(ws + (size_t)2 * BB * LL * DD);
    float* Wdt1T = ws + (size_t)2 * BB * LL * DD + (size_t)2 * BB * LL * NN;
    float* Wdt2T = Wdt1T + 65536;
    float* WBCT  = Wdt2T + 65536;

    prep_kernel<<<256, 256, 0, stream>>>(W_dt1, W_dt2, W_B, W_C, Wdt1T, Wdt2T, WBCT);
    proj_kernel<<<BB * (LL / ROWS), 256, 0, stream>>>(x, conv_w, conv_b, Wdt1T, Wdt2T,
                                                      b_dt, WBCT, xdt, bc);
    scan_kernel<<<BB * (DD / 4), 64, 0, stream>>>(xdt, bc, A_log, Dparam, y);
}

// Round 3
// 743.376 us; speedup vs baseline: 2.0486x; 2.0486x over previous
//
#include <hip/hip_runtime.h>
#include <hip/hip_bf16.h>

// Problem dims (fixed by setup_inputs)
#define BB 2
#define LL 4096
#define DD 1024
#define NN 16
#define RR 64
#define KK 4
#define ROWS 8   // rows (l) per proj block

#define T_CH 64            // scan chunk (timesteps) staged in LDS
#define NCH (LL / T_CH)    // 64 chunks

// ---------------- helpers ----------------

__device__ __forceinline__ float med3f(float x, float lo, float hi) {
    return __builtin_amdgcn_fmed3f(x, lo, hi);
}

template<int CTRL>
__device__ __forceinline__ float dpp_ror(float v) {
    int r = __builtin_amdgcn_update_dpp(0, __builtin_bit_cast(int, v), CTRL, 0xf, 0xf, true);
    return __builtin_bit_cast(float, r);
}

__device__ __forceinline__ float silu_f(float z) {
    float e = __expf(-z);
    return z * __builtin_amdgcn_rcpf(1.0f + e);
}

__device__ __forceinline__ float softplus_f(float z) {
    // log(1+exp(z)) = max(z,0) + log(1+exp(-|z|))
    float e = __expf(-fabsf(z));
    return fmaxf(z, 0.0f) + __logf(1.0f + e);
}

// async global->LDS, 16B per lane; LDS dest is wave-uniform base + lane*16
__device__ __forceinline__ void gload_lds16(const void* g, void* l) {
    __builtin_amdgcn_global_load_lds(
        (__attribute__((address_space(1))) void*)g,
        (__attribute__((address_space(3))) void*)l, 16, 0, 0);
}

// ---------------- prep: weight transposes ----------------
// Wdt1T[k*64+r] = W_dt1[r*1024+k]
// Wdt2T[r*1024+d] = W_dt2[d*64+r]
// WBCT[k*32+o] = o<16 ? W_B[o*1024+k] : W_C[(o-16)*1024+k]
__global__ __launch_bounds__(256) void prep_kernel(
    const float* __restrict__ Wdt1, const float* __restrict__ Wdt2,
    const float* __restrict__ WB, const float* __restrict__ WC,
    float* __restrict__ Wdt1T, float* __restrict__ Wdt2T, float* __restrict__ WBCT)
{
    int i = blockIdx.x * 256 + threadIdx.x;   // up to 65536
    if (i < 65536) {
        int k = i >> 6, r = i & 63;
        Wdt1T[i] = Wdt1[r * 1024 + k];
    }
    if (i < 65536) {
        int r = i >> 10, d = i & 1023;
        Wdt2T[i] = Wdt2[d * 64 + r];
    }
    if (i < 32768) {
        int k = i >> 5, o = i & 31;
        WBCT[i] = (o < 16) ? WB[o * 1024 + k] : WC[(o - 16) * 1024 + k];
    }
}

// ---------------- proj: conv + silu + dt/B/C projections ----------------
__global__ __launch_bounds__(256) void proj_kernel(
    const float* __restrict__ x,
    const float* __restrict__ conv_w, const float* __restrict__ conv_b,
    const float* __restrict__ Wdt1T, const float* __restrict__ Wdt2T,
    const float* __restrict__ b_dt, const float* __restrict__ WBCT,
    float2* __restrict__ xdt, float2* __restrict__ bc)
{
    __shared__ alignas(16) float xc8[1024 * ROWS];   // [d][row], 32KB
    __shared__ alignas(16) float part[2048];         // 8KB, reused A/C
    __shared__ alignas(16) float dtpre[64 * ROWS];   // [r][row], 2KB

    const int t = threadIdx.x;
    const int blk = blockIdx.x;             // 0..1023
    const int b = blk >> 9;                 // 512 blocks per batch
    const int l0 = (blk & 511) << 3;        // row base
    const float* xb = x + (size_t)b * LL * DD;

    // ---- conv + silu, 4 d's per thread, 8 rows each ----
    float xc_reg[4][ROWS];
    #pragma unroll
    for (int dd = 0; dd < 4; ++dd) {
        int d = t + dd * 256;
        float4 w4 = reinterpret_cast<const float4*>(conv_w)[d];
        float cb = conv_b[d];
        float xv[ROWS + 3];
        #pragma unroll
        for (int j = 0; j < ROWS + 3; ++j) {
            int l = l0 - 3 + j;
            xv[j] = (l >= 0) ? xb[(size_t)l * DD + d] : 0.0f;
        }
        #pragma unroll
        for (int r = 0; r < ROWS; ++r) {
            float s = cb + xv[r] * w4.x + xv[r + 1] * w4.y + xv[r + 2] * w4.z + xv[r + 3] * w4.w;
            float v = silu_f(s);
            xc_reg[dd][r] = v;
        }
        float4 lo = make_float4(xc_reg[dd][0], xc_reg[dd][1], xc_reg[dd][2], xc_reg[dd][3]);
        float4 hi = make_float4(xc_reg[dd][4], xc_reg[dd][5], xc_reg[dd][6], xc_reg[dd][7]);
        reinterpret_cast<float4*>(&xc8[d * ROWS])[0] = lo;
        reinterpret_cast<float4*>(&xc8[d * ROWS])[1] = hi;
    }
    __syncthreads();

    const float4* xr4 = reinterpret_cast<const float4*>(xc8);

    // ---- phase A: dt_pre[r] = sum_k xc[k] * Wdt1T[k][r] ----
    {
        int r = t & 63, seg = t >> 6;           // 4 segs x 256 k
        float acc[ROWS];
        #pragma unroll
        for (int q = 0; q < ROWS; ++q) acc[q] = 0.0f;
        const float* wp = Wdt1T + (size_t)(seg * 256) * 64 + r;
        int kbase = seg * 256;
        for (int i = 0; i < 256; ++i) {
            float wv = wp[(size_t)i * 64];
            float4 a = xr4[(kbase + i) * 2];
            float4 c = xr4[(kbase + i) * 2 + 1];
            acc[0] += a.x * wv; acc[1] += a.y * wv; acc[2] += a.z * wv; acc[3] += a.w * wv;
            acc[4] += c.x * wv; acc[5] += c.y * wv; acc[6] += c.z * wv; acc[7] += c.w * wv;
        }
        #pragma unroll
        for (int q = 0; q < ROWS; ++q) part[seg * 512 + r * 8 + q] = acc[q];
    }
    __syncthreads();
    {
        // reduce 4 segs -> dtpre[r*8+row]; 512 values, 256 threads x 2
        int idx = t;
        #pragma unroll
        for (int rep = 0; rep < 2; ++rep, idx += 256) {
            float s = part[idx] + part[512 + idx] + part[1024 + idx] + part[1536 + idx];
            dtpre[idx] = s;
        }
    }
    __syncthreads();

    // ---- phase B: dt[d] = softplus(sum_r dtpre[r]*Wdt2T[r][d] + b_dt[d]); write xdt ----
    const float4* dp4 = reinterpret_cast<const float4*>(dtpre);
    #pragma unroll
    for (int dd = 0; dd < 4; ++dd) {
        int d = t + dd * 256;
        float bd = b_dt[d];
        float acc[ROWS];
        #pragma unroll
        for (int q = 0; q < ROWS; ++q) acc[q] = bd;
        const float* wp = Wdt2T + d;
        for (int r = 0; r < 64; ++r) {
            float wv = wp[(size_t)r * 1024];
            float4 p0 = dp4[r * 2];
            float4 p1 = dp4[r * 2 + 1];
            acc[0] += p0.x * wv; acc[1] += p0.y * wv; acc[2] += p0.z * wv; acc[3] += p0.w * wv;
            acc[4] += p1.x * wv; acc[5] += p1.y * wv; acc[6] += p1.z * wv; acc[7] += p1.w * wv;
        }
        #pragma unroll
        for (int row = 0; row < ROWS; ++row) {
            float sp = softplus_f(acc[row]);
            xdt[(size_t)(b * LL + l0 + row) * DD + d] = make_float2(xc_reg[dd][row], sp);
        }
    }
    // part was last READ before the barrier after phase A reduce; safe to rewrite in C.

    // ---- phase C: B_ssm/C_ssm ----
    {
        int o = t & 31, seg = t >> 5;           // 8 segs x 128 k
        float acc[ROWS];
        #pragma unroll
        for (int q = 0; q < ROWS; ++q) acc[q] = 0.0f;
        const float* wp = WBCT + (size_t)(seg * 128) * 32 + o;
        int kbase = seg * 128;
        for (int i = 0; i < 128; ++i) {
            float wv = wp[(size_t)i * 32];
            float4 a = xr4[(kbase + i) * 2];
            float4 c = xr4[(kbase + i) * 2 + 1];
            acc[0] += a.x * wv; acc[1] += a.y * wv; acc[2] += a.z * wv; acc[3] += a.w * wv;
            acc[4] += c.x * wv; acc[5] += c.y * wv; acc[6] += c.z * wv; acc[7] += c.w * wv;
        }
        #pragma unroll
        for (int q = 0; q < ROWS; ++q) part[seg * 256 + o * 8 + q] = acc[q];
    }
    __syncthreads();
    if (t < 128) {
        int n = t & 15, row = t >> 4;
        float Bv = 0.0f, Cv = 0.0f;
        #pragma unroll
        for (int seg = 0; seg < 8; ++seg) {
            Bv += part[seg * 256 + n * 8 + row];
            Cv += part[seg * 256 + (n + 16) * 8 + row];
        }
        bc[(size_t)(b * LL + l0 + row) * NN + n] = make_float2(Bv, Cv);
    }
}

// ---------------- scan: sequential over L, lane = (b, d, n) ----------------
// LDS double-buffered chunks of T_CH steps; global_load_lds prefetch with
// counted vmcnt so next chunk's loads stay in flight under current compute.
__global__ __launch_bounds__(64) void scan_kernel(
    const float2* __restrict__ xdt, const float2* __restrict__ bc,
    const float* __restrict__ A_log, const float* __restrict__ Dparam,
    float* __restrict__ y)
{
    // xbuf: [t][dloc] float2 -> byte t*32 + dloc*8  (2KB per buffer)
    // bcbuf: [t][n]   float2 -> byte t*128 + n*8    (8KB per buffer)
    __shared__ alignas(16) float xbuf[2][T_CH * 8];
    __shared__ alignas(16) float bcbuf[2][T_CH * 32];

    const int w = blockIdx.x;       // 0..511
    const int b = w >> 8;
    const int dbase = (w & 255) << 2;
    const int lane = threadIdx.x;   // 0..63
    const int n = lane & 15;
    const int dl = lane >> 4;
    const int d = dbase + dl;

    // A2 = A * log2(e) so the per-step exp is a bare v_exp_f32 (2^x)
    const float A2 = -__expf(A_log[d * NN + n]) * 1.4426950408889634f;
    const float Dp = Dparam[d];

    const float2* xg = xdt + (size_t)b * LL * DD + dbase;  // [l][dbase..dbase+3]
    const float2* bg = bc + (size_t)b * LL * NN;           // [l][0..15]
    float* yp = y + (size_t)b * LL * DD + d;

    // staging lane mapping (lane i writes LDS byte i*16 -> linear order required)
    const int tx = lane >> 1, hx = lane & 1;   // xdt: 32 t's per instr (32B/row)
    const int tb = lane >> 3, pb = lane & 7;   // bc: 8 t's per instr (128B/row)

    // prologue: stage chunk 0 into buf 0
    {
        const char* gx = (const char*)(xg + (size_t)tx * DD) + hx * 16;
        gload_lds16(gx, &xbuf[0][0]);
        gload_lds16(gx + (size_t)32 * DD * 8, &xbuf[0][32 * 8]);
        const char* gb = (const char*)(bg + (size_t)tb * NN) + pb * 16;
        #pragma unroll
        for (int j = 0; j < 8; ++j)
            gload_lds16(gb + (size_t)j * 8 * NN * 8, &bcbuf[0][j * 8 * 32]);
    }

    float h = 0.0f;
    #pragma unroll 1
    for (int c = 0; c < NCH; ++c) {
        const int cur = c & 1;
        if (c + 1 < NCH) {
            const int nxt = cur ^ 1;
            const size_t l1 = (size_t)(c + 1) * T_CH;
            const char* gx = (const char*)(xg + (l1 + tx) * DD) + hx * 16;
            gload_lds16(gx, &xbuf[nxt][0]);
            gload_lds16(gx + (size_t)32 * DD * 8, &xbuf[nxt][32 * 8]);
            const char* gb = (const char*)(bg + (l1 + tb) * NN) + pb * 16;
            #pragma unroll
            for (int j = 0; j < 8; ++j)
                gload_lds16(gb + (size_t)j * 8 * NN * 8, &bcbuf[nxt][j * 8 * 32]);
            // all but the 10 just-issued loads must be done => chunk c resident
            asm volatile("s_waitcnt vmcnt(10)" ::: "memory");
        } else {
            asm volatile("s_waitcnt vmcnt(0)" ::: "memory");
        }

        const float2* xl = (const float2*)&xbuf[cur][0];
        const float2* bl = (const float2*)&bcbuf[cur][0];
        float* yc = yp + (size_t)c * T_CH * DD;
        #pragma unroll 16
        for (int t = 0; t < T_CH; ++t) {
            float2 xz = xl[t * 4 + dl];    // broadcast across 16 lanes
            float2 bcv = bl[t * 16 + n];   // broadcast across 4 lanes
            float xv = xz.x, dt = xz.y;                  // dt >= 0 (softplus)
            float dtA = fmaxf(dt * A2, -14.426950408889634f); // clip(dt*A,-10,0) in log2 domain
            float Abar = fminf(exp2f(dtA), 0.999f);      // clip(exp,0,0.999)
            float tt = fminf(dt, 1.0f) * bcv.x;          // clip(dt,0,1) * B
            tt = med3f(tt, -10.0f, 10.0f);               // clip B_bar
            h = fmaf(Abar, h, tt * xv);
            h = med3f(h, -100.0f, 100.0f);
            float p = h * bcv.y;
            p += dpp_ror<0x121>(p);   // row_ror:1 (16-lane group all-reduce)
            p += dpp_ror<0x122>(p);   // row_ror:2
            p += dpp_ror<0x124>(p);   // row_ror:4
            p += dpp_ror<0x128>(p);   // row_ror:8
            if (n == 0) {
                float yv = fmaf(Dp, xv, p);
                yc[(size_t)t * DD] = med3f(yv, -50.0f, 50.0f);
            }
        }
    }
}

// ---------------- launch ----------------
extern "C" void kernel_launch(void* const* d_in, const int* in_sizes, int n_in,
                              void* d_out, int out_size, void* d_ws, size_t ws_size,
                              hipStream_t stream) {
    const float* x      = (const float*)d_in[0];
    const float* A_log  = (const float*)d_in[1];
    const float* Dparam = (const float*)d_in[2];
    const float* W_dt1  = (const float*)d_in[3];
    const float* W_dt2  = (const float*)d_in[4];
    const float* b_dt   = (const float*)d_in[5];
    const float* W_B    = (const float*)d_in[6];
    const float* W_C    = (const float*)d_in[7];
    const float* conv_w = (const float*)d_in[8];
    const float* conv_b = (const float*)d_in[9];
    float* y = (float*)d_out;

    float* ws = (float*)d_ws;
    // layout (floats): xdt 16M | bc 256K | Wdt1T 64K | Wdt2T 64K | WBCT 32K
    float2* xdt  = (float2*)ws;
    float2* bc   = (float2*)(ws + (size_t)2 * BB * LL * DD);
    float* Wdt1T = ws + (size_t)2 * BB * LL * DD + (size_t)2 * BB * LL * NN;
    float* Wdt2T = Wdt1T + 65536;
    float* WBCT  = Wdt2T + 65536;

    prep_kernel<<<256, 256, 0, stream>>>(W_dt1, W_dt2, W_B, W_C, Wdt1T, Wdt2T, WBCT);
    proj_kernel<<<BB * (LL / ROWS), 256, 0, stream>>>(x, conv_w, conv_b, Wdt1T, Wdt2T,
                                                      b_dt, WBCT, xdt, bc);
    scan_kernel<<<BB * (DD / 4), 64, 0, stream>>>(xdt, bc, A_log, Dparam, y);
}

// Round 4
// 534.273 us; speedup vs baseline: 2.8504x; 1.3914x over previous
//
#include <hip/hip_runtime.h>
#include <hip/hip_bf16.h>

// Problem dims (fixed by setup_inputs)
#define BB 2
#define LL 4096
#define DD 1024
#define NN 16
#define RR 64
#define KK 4
#define ROWS 8   // rows (l) per proj block

#define T_CH 64            // scan chunk (timesteps) staged in LDS
#define NCH (LL / T_CH)    // 64 chunks

// ---------------- helpers ----------------

__device__ __forceinline__ float med3f(float x, float lo, float hi) {
    return __builtin_amdgcn_fmed3f(x, lo, hi);
}

template<int CTRL>
__device__ __forceinline__ float dpp_ror(float v) {
    int r = __builtin_amdgcn_update_dpp(0, __builtin_bit_cast(int, v), CTRL, 0xf, 0xf, true);
    return __builtin_bit_cast(float, r);
}

__device__ __forceinline__ float silu_f(float z) {
    float e = __expf(-z);
    return z * __builtin_amdgcn_rcpf(1.0f + e);
}

__device__ __forceinline__ float softplus_f(float z) {
    // log(1+exp(z)) = max(z,0) + log(1+exp(-|z|))
    float e = __expf(-fabsf(z));
    return fmaxf(z, 0.0f) + __logf(1.0f + e);
}

// async global->LDS, 16B per lane; LDS dest is wave-uniform base + lane*16
__device__ __forceinline__ void gload_lds16(const void* g, void* l) {
    __builtin_amdgcn_global_load_lds(
        (__attribute__((address_space(1))) void*)g,
        (__attribute__((address_space(3))) void*)l, 16, 0, 0);
}

// ---------------- prep: weight transposes ----------------
// Wdt1T[k*64+r] = W_dt1[r*1024+k]
// Wdt2T[r*1024+d] = W_dt2[d*64+r]
// WBCT[k*32+o] = o<16 ? W_B[o*1024+k] : W_C[(o-16)*1024+k]
__global__ __launch_bounds__(256) void prep_kernel(
    const float* __restrict__ Wdt1, const float* __restrict__ Wdt2,
    const float* __restrict__ WB, const float* __restrict__ WC,
    float* __restrict__ Wdt1T, float* __restrict__ Wdt2T, float* __restrict__ WBCT)
{
    int i = blockIdx.x * 256 + threadIdx.x;   // up to 65536
    if (i < 65536) {
        int k = i >> 6, r = i & 63;
        Wdt1T[i] = Wdt1[r * 1024 + k];
    }
    if (i < 65536) {
        int r = i >> 10, d = i & 1023;
        Wdt2T[i] = Wdt2[d * 64 + r];
    }
    if (i < 32768) {
        int k = i >> 5, o = i & 31;
        WBCT[i] = (o < 16) ? WB[o * 1024 + k] : WC[(o - 16) * 1024 + k];
    }
}

// ---------------- proj: conv + silu + dt/B/C projections ----------------
__global__ __launch_bounds__(256) void proj_kernel(
    const float* __restrict__ x,
    const float* __restrict__ conv_w, const float* __restrict__ conv_b,
    const float* __restrict__ Wdt1T, const float* __restrict__ Wdt2T,
    const float* __restrict__ b_dt, const float* __restrict__ WBCT,
    float2* __restrict__ xdt, float2* __restrict__ bc)
{
    __shared__ alignas(16) float xc8[1024 * ROWS];   // [d][row], 32KB
    __shared__ alignas(16) float part[2048];         // 8KB, reused A/C
    __shared__ alignas(16) float dtpre[64 * ROWS];   // [r][row], 2KB

    const int t = threadIdx.x;
    const int blk = blockIdx.x;             // 0..1023
    const int b = blk >> 9;                 // 512 blocks per batch
    const int l0 = (blk & 511) << 3;        // row base
    const float* xb = x + (size_t)b * LL * DD;

    // ---- conv + silu, 4 d's per thread, 8 rows each ----
    float xc_reg[4][ROWS];
    #pragma unroll
    for (int dd = 0; dd < 4; ++dd) {
        int d = t + dd * 256;
        float4 w4 = reinterpret_cast<const float4*>(conv_w)[d];
        float cb = conv_b[d];
        float xv[ROWS + 3];
        #pragma unroll
        for (int j = 0; j < ROWS + 3; ++j) {
            int l = l0 - 3 + j;
            xv[j] = (l >= 0) ? xb[(size_t)l * DD + d] : 0.0f;
        }
        #pragma unroll
        for (int r = 0; r < ROWS; ++r) {
            float s = cb + xv[r] * w4.x + xv[r + 1] * w4.y + xv[r + 2] * w4.z + xv[r + 3] * w4.w;
            float v = silu_f(s);
            xc_reg[dd][r] = v;
        }
        float4 lo = make_float4(xc_reg[dd][0], xc_reg[dd][1], xc_reg[dd][2], xc_reg[dd][3]);
        float4 hi = make_float4(xc_reg[dd][4], xc_reg[dd][5], xc_reg[dd][6], xc_reg[dd][7]);
        reinterpret_cast<float4*>(&xc8[d * ROWS])[0] = lo;
        reinterpret_cast<float4*>(&xc8[d * ROWS])[1] = hi;
    }
    __syncthreads();

    const float4* xr4 = reinterpret_cast<const float4*>(xc8);

    // ---- phase A: dt_pre[r] = sum_k xc[k] * Wdt1T[k][r] ----
    {
        int r = t & 63, seg = t >> 6;           // 4 segs x 256 k
        float acc[ROWS];
        #pragma unroll
        for (int q = 0; q < ROWS; ++q) acc[q] = 0.0f;
        const float* wp = Wdt1T + (size_t)(seg * 256) * 64 + r;
        int kbase = seg * 256;
        for (int i = 0; i < 256; ++i) {
            float wv = wp[(size_t)i * 64];
            float4 a = xr4[(kbase + i) * 2];
            float4 c = xr4[(kbase + i) * 2 + 1];
            acc[0] += a.x * wv; acc[1] += a.y * wv; acc[2] += a.z * wv; acc[3] += a.w * wv;
            acc[4] += c.x * wv; acc[5] += c.y * wv; acc[6] += c.z * wv; acc[7] += c.w * wv;
        }
        #pragma unroll
        for (int q = 0; q < ROWS; ++q) part[seg * 512 + r * 8 + q] = acc[q];
    }
    __syncthreads();
    {
        // reduce 4 segs -> dtpre[r*8+row]; 512 values, 256 threads x 2
        int idx = t;
        #pragma unroll
        for (int rep = 0; rep < 2; ++rep, idx += 256) {
            float s = part[idx] + part[512 + idx] + part[1024 + idx] + part[1536 + idx];
            dtpre[idx] = s;
        }
    }
    __syncthreads();

    // ---- phase B: dt[d] = softplus(sum_r dtpre[r]*Wdt2T[r][d] + b_dt[d]); write xdt ----
    const float4* dp4 = reinterpret_cast<const float4*>(dtpre);
    #pragma unroll
    for (int dd = 0; dd < 4; ++dd) {
        int d = t + dd * 256;
        float bd = b_dt[d];
        float acc[ROWS];
        #pragma unroll
        for (int q = 0; q < ROWS; ++q) acc[q] = bd;
        const float* wp = Wdt2T + d;
        for (int r = 0; r < 64; ++r) {
            float wv = wp[(size_t)r * 1024];
            float4 p0 = dp4[r * 2];
            float4 p1 = dp4[r * 2 + 1];
            acc[0] += p0.x * wv; acc[1] += p0.y * wv; acc[2] += p0.z * wv; acc[3] += p0.w * wv;
            acc[4] += p1.x * wv; acc[5] += p1.y * wv; acc[6] += p1.z * wv; acc[7] += p1.w * wv;
        }
        #pragma unroll
        for (int row = 0; row < ROWS; ++row) {
            float sp = softplus_f(acc[row]);
            xdt[(size_t)(b * LL + l0 + row) * DD + d] = make_float2(xc_reg[dd][row], sp);
        }
    }
    // part was last READ before the barrier after phase A reduce; safe to rewrite in C.

    // ---- phase C: B_ssm/C_ssm ----
    {
        int o = t & 31, seg = t >> 5;           // 8 segs x 128 k
        float acc[ROWS];
        #pragma unroll
        for (int q = 0; q < ROWS; ++q) acc[q] = 0.0f;
        const float* wp = WBCT + (size_t)(seg * 128) * 32 + o;
        int kbase = seg * 128;
        for (int i = 0; i < 128; ++i) {
            float wv = wp[(size_t)i * 32];
            float4 a = xr4[(kbase + i) * 2];
            float4 c = xr4[(kbase + i) * 2 + 1];
            acc[0] += a.x * wv; acc[1] += a.y * wv; acc[2] += a.z * wv; acc[3] += a.w * wv;
            acc[4] += c.x * wv; acc[5] += c.y * wv; acc[6] += c.z * wv; acc[7] += c.w * wv;
        }
        #pragma unroll
        for (int q = 0; q < ROWS; ++q) part[seg * 256 + o * 8 + q] = acc[q];
    }
    __syncthreads();
    if (t < 128) {
        int n = t & 15, row = t >> 4;
        float Bv = 0.0f, Cv = 0.0f;
        #pragma unroll
        for (int seg = 0; seg < 8; ++seg) {
            Bv += part[seg * 256 + n * 8 + row];
            Cv += part[seg * 256 + (n + 16) * 8 + row];
        }
        bc[(size_t)(b * LL + l0 + row) * NN + n] = make_float2(Bv, Cv);
    }
}

// ---------------- scan: sequential over L, lane = (b, d, n) ----------------
// LDS double-buffered input chunks; branchless inner loop (y captured per-lane
// via cndmask, 4 bulk stores per chunk) so each chunk is one basic block and
// the scheduler can pipeline ds_reads across steps.
__global__ __launch_bounds__(64) void scan_kernel(
    const float2* __restrict__ xdt, const float2* __restrict__ bc,
    const float* __restrict__ A_log, const float* __restrict__ Dparam,
    float* __restrict__ y)
{
    // xbuf: [t][dloc] float2 -> byte t*32 + dloc*8  (2KB per buffer)
    // bcbuf: [t][n]   float2 -> byte t*128 + n*8    (8KB per buffer)
    __shared__ alignas(16) float xbuf[2][T_CH * 8];
    __shared__ alignas(16) float bcbuf[2][T_CH * 32];

    const int w = blockIdx.x;       // 0..511
    const int b = w >> 8;
    const int dbase = (w & 255) << 2;
    const int lane = threadIdx.x;   // 0..63
    const int n = lane & 15;
    const int dl = lane >> 4;
    const int d = dbase + dl;

    // A2 = A * log2(e) so the per-step exp is a bare v_exp_f32 (2^x)
    const float A2 = -__expf(A_log[d * NN + n]) * 1.4426950408889634f;
    const float Dp = Dparam[d];

    const float2* xg = xdt + (size_t)b * LL * DD + dbase;  // [l][dbase..dbase+3]
    const float2* bg = bc + (size_t)b * LL * NN;           // [l][0..15]
    float* yb = y + (size_t)b * LL * DD + dbase + dl;      // this lane's column

    // staging lane mapping (lane i writes LDS byte i*16 -> linear order required)
    const int tx = lane >> 1, hx = lane & 1;   // xdt: 32 t's per instr (32B/row)
    const int tb = lane >> 3, pb = lane & 7;   // bc: 8 t's per instr (128B/row)

    // prologue: stage chunk 0 into buf 0
    {
        const char* gx = (const char*)(xg + (size_t)tx * DD) + hx * 16;
        gload_lds16(gx, &xbuf[0][0]);
        gload_lds16(gx + (size_t)32 * DD * 8, &xbuf[0][32 * 8]);
        const char* gb = (const char*)(bg + (size_t)tb * NN) + pb * 16;
        #pragma unroll
        for (int j = 0; j < 8; ++j)
            gload_lds16(gb + (size_t)j * 8 * NN * 8, &bcbuf[0][j * 8 * 32]);
    }

    float h = 0.0f;
    #pragma unroll 1
    for (int c = 0; c < NCH; ++c) {
        const int cur = c & 1;
        if (c + 1 < NCH) {
            const int nxt = cur ^ 1;
            const size_t l1 = (size_t)(c + 1) * T_CH;
            const char* gx = (const char*)(xg + (l1 + tx) * DD) + hx * 16;
            gload_lds16(gx, &xbuf[nxt][0]);
            gload_lds16(gx + (size_t)32 * DD * 8, &xbuf[nxt][32 * 8]);
            const char* gb = (const char*)(bg + (l1 + tb) * NN) + pb * 16;
            #pragma unroll
            for (int j = 0; j < 8; ++j)
                gload_lds16(gb + (size_t)j * 8 * NN * 8, &bcbuf[nxt][j * 8 * 32]);
            // all but the 10 just-issued loads must be done => chunk c resident
            asm volatile("s_waitcnt vmcnt(10)" ::: "memory");
        } else {
            asm volatile("s_waitcnt vmcnt(0)" ::: "memory");
        }

        const float2* xl = (const float2*)&xbuf[cur][0];
        const float2* bl = (const float2*)&bcbuf[cur][0];

        float yreg[4];
        #pragma unroll
        for (int tq = 0; tq < 4; ++tq) {
            float yr = 0.0f;
            #pragma unroll
            for (int ts = 0; ts < 16; ++ts) {
                const int t = tq * 16 + ts;
                float2 xz = xl[t * 4 + dl];    // broadcast across 16 lanes
                float2 bcv = bl[t * 16 + n];   // broadcast across 4 lanes
                float xv = xz.x, dt = xz.y;                  // dt >= 0 (softplus)
                float dtA = fmaxf(dt * A2, -14.426950408889634f); // clip in log2 domain
                float Abar = fminf(exp2f(dtA), 0.999f);      // clip(exp,0,0.999)
                float tt = fminf(dt, 1.0f) * bcv.x;          // clip(dt,0,1) * B
                tt = med3f(tt, -10.0f, 10.0f);               // clip B_bar
                h = fmaf(Abar, h, tt * xv);
                h = med3f(h, -100.0f, 100.0f);
                float p = h * bcv.y;
                p += dpp_ror<0x121>(p);   // 16-lane group all-reduce
                p += dpp_ror<0x122>(p);
                p += dpp_ror<0x124>(p);
                p += dpp_ror<0x128>(p);
                float yv = med3f(fmaf(Dp, xv, p), -50.0f, 50.0f);
                // branchless capture: lane n keeps step ts of this 16-group
                yr = (n == ts) ? yv : yr;
            }
            yreg[tq] = yr;
        }

        // 4 bulk stores: lane (dl,n) writes y[c*64 + tq*16 + n][dbase+dl]
        const size_t l0s = (size_t)c * T_CH;
        #pragma unroll
        for (int tq = 0; tq < 4; ++tq)
            yb[(l0s + tq * 16 + n) * DD] = yreg[tq];
    }
}

// ---------------- launch ----------------
extern "C" void kernel_launch(void* const* d_in, const int* in_sizes, int n_in,
                              void* d_out, int out_size, void* d_ws, size_t ws_size,
                              hipStream_t stream) {
    const float* x      = (const float*)d_in[0];
    const float* A_log  = (const float*)d_in[1];
    const float* Dparam = (const float*)d_in[2];
    const float* W_dt1  = (const float*)d_in[3];
    const float* W_dt2  = (const float*)d_in[4];
    const float* b_dt   = (const float*)d_in[5];
    const float* W_B    = (const float*)d_in[6];
    const float* W_C    = (const float*)d_in[7];
    const float* conv_w = (const float*)d_in[8];
    const float* conv_b = (const float*)d_in[9];
    float* y = (float*)d_out;

    float* ws = (float*)d_ws;
    // layout (floats): xdt 16M | bc 256K | Wdt1T 64K | Wdt2T 64K | WBCT 32K
    float2* xdt  = (float2*)ws;
    float2* bc   = (float2*)(ws + (size_t)2 * BB * LL * DD);
    float* Wdt1T = ws + (size_t)2 * BB * LL * DD + (size_t)2 * BB * LL * NN;
    float* Wdt2T = Wdt1T + 65536;
    float* WBCT  = Wdt2T + 65536;

    prep_kernel<<<256, 256, 0, stream>>>(W_dt1, W_dt2, W_B, W_C, Wdt1T, Wdt2T, WBCT);
    proj_kernel<<<BB * (LL / ROWS), 256, 0, stream>>>(x, conv_w, conv_b, Wdt1T, Wdt2T,
                                                      b_dt, WBCT, xdt, bc);
    scan_kernel<<<BB * (DD / 4), 64, 0, stream>>>(xdt, bc, A_log, Dparam, y);
}

// Round 6
// 491.910 us; speedup vs baseline: 3.0959x; 1.0861x over previous
//
#include <hip/hip_runtime.h>
#include <hip/hip_bf16.h>

// Problem dims (fixed by setup_inputs)
#define BB 2
#define LL 4096
#define DD 1024
#define NN 16
#define RR 64
#define KK 4
#define ROWS 8   // rows (l) per proj block

#define T_CH 32            // scan chunk (timesteps) kept in registers
#define NCH (LL / T_CH)    // 128 chunks

// ---------------- helpers ----------------

__device__ __forceinline__ float med3f(float x, float lo, float hi) {
    return __builtin_amdgcn_fmed3f(x, lo, hi);
}

template<int CTRL>
__device__ __forceinline__ float dpp_ror(float v) {
    int r = __builtin_amdgcn_update_dpp(0, __builtin_bit_cast(int, v), CTRL, 0xf, 0xf, true);
    return __builtin_bit_cast(float, r);
}

__device__ __forceinline__ float silu_f(float z) {
    float e = __expf(-z);
    return z * __builtin_amdgcn_rcpf(1.0f + e);
}

__device__ __forceinline__ float softplus_f(float z) {
    // log(1+exp(z)) = max(z,0) + log(1+exp(-|z|))
    float e = __expf(-fabsf(z));
    return fmaxf(z, 0.0f) + __logf(1.0f + e);
}

// ---------------- prep: weight transposes ----------------
// Wdt1T[k*64+r] = W_dt1[r*1024+k]
// Wdt2T[r*1024+d] = W_dt2[d*64+r]
// WBCT[k*32+o] = o<16 ? W_B[o*1024+k] : W_C[(o-16)*1024+k]
__global__ __launch_bounds__(256) void prep_kernel(
    const float* __restrict__ Wdt1, const float* __restrict__ Wdt2,
    const float* __restrict__ WB, const float* __restrict__ WC,
    float* __restrict__ Wdt1T, float* __restrict__ Wdt2T, float* __restrict__ WBCT)
{
    int i = blockIdx.x * 256 + threadIdx.x;   // up to 65536
    if (i < 65536) {
        int k = i >> 6, r = i & 63;
        Wdt1T[i] = Wdt1[r * 1024 + k];
    }
    if (i < 65536) {
        int r = i >> 10, d = i & 1023;
        Wdt2T[i] = Wdt2[d * 64 + r];
    }
    if (i < 32768) {
        int k = i >> 5, o = i & 31;
        WBCT[i] = (o < 16) ? WB[o * 1024 + k] : WC[(o - 16) * 1024 + k];
    }
}

// ---------------- proj: conv + silu + dt/B/C projections ----------------
// Outputs in scan-native transposed layouts:
//   xdtT[((b*NCH + c)*DD + d)*T_CH + t] = {x_conv, dt}   (c = l/32, t = l%32)
//   bcT [((b*NCH + c)*NN + n)*T_CH + t] = {B, C}
__global__ __launch_bounds__(256) void proj_kernel(
    const float* __restrict__ x,
    const float* __restrict__ conv_w, const float* __restrict__ conv_b,
    const float* __restrict__ Wdt1T, const float* __restrict__ Wdt2T,
    const float* __restrict__ b_dt, const float* __restrict__ WBCT,
    float2* __restrict__ xdtT, float2* __restrict__ bcT)
{
    __shared__ alignas(16) float xc8[1024 * ROWS];   // [d][row], 32KB
    __shared__ alignas(16) float part[2048];         // 8KB, reused A/C
    __shared__ alignas(16) float dtpre[64 * ROWS];   // [r][row], 2KB

    const int t = threadIdx.x;
    const int blk = blockIdx.x;             // 0..1023
    const int b = blk >> 9;                 // 512 blocks per batch
    const int l0 = (blk & 511) << 3;        // row base
    const int ch = l0 >> 5;                 // scan chunk (8 rows lie in one chunk)
    const int tt0 = l0 & 31;                // t-offset within chunk
    const float* xb = x + (size_t)b * LL * DD;

    // ---- conv + silu, 4 d's per thread, 8 rows each ----
    float xc_reg[4][ROWS];
    #pragma unroll
    for (int dd = 0; dd < 4; ++dd) {
        int d = t + dd * 256;
        float4 w4 = reinterpret_cast<const float4*>(conv_w)[d];
        float cb = conv_b[d];
        float xv[ROWS + 3];
        #pragma unroll
        for (int j = 0; j < ROWS + 3; ++j) {
            int l = l0 - 3 + j;
            xv[j] = (l >= 0) ? xb[(size_t)l * DD + d] : 0.0f;
        }
        #pragma unroll
        for (int r = 0; r < ROWS; ++r) {
            float s = cb + xv[r] * w4.x + xv[r + 1] * w4.y + xv[r + 2] * w4.z + xv[r + 3] * w4.w;
            float v = silu_f(s);
            xc_reg[dd][r] = v;
        }
        float4 lo = make_float4(xc_reg[dd][0], xc_reg[dd][1], xc_reg[dd][2], xc_reg[dd][3]);
        float4 hi = make_float4(xc_reg[dd][4], xc_reg[dd][5], xc_reg[dd][6], xc_reg[dd][7]);
        reinterpret_cast<float4*>(&xc8[d * ROWS])[0] = lo;
        reinterpret_cast<float4*>(&xc8[d * ROWS])[1] = hi;
    }
    __syncthreads();

    const float4* xr4 = reinterpret_cast<const float4*>(xc8);

    // ---- phase A: dt_pre[r] = sum_k xc[k] * Wdt1T[k][r] ----
    {
        int r = t & 63, seg = t >> 6;           // 4 segs x 256 k
        float acc[ROWS];
        #pragma unroll
        for (int q = 0; q < ROWS; ++q) acc[q] = 0.0f;
        const float* wp = Wdt1T + (size_t)(seg * 256) * 64 + r;
        int kbase = seg * 256;
        for (int i = 0; i < 256; ++i) {
            float wv = wp[(size_t)i * 64];
            float4 a = xr4[(kbase + i) * 2];
            float4 c = xr4[(kbase + i) * 2 + 1];
            acc[0] += a.x * wv; acc[1] += a.y * wv; acc[2] += a.z * wv; acc[3] += a.w * wv;
            acc[4] += c.x * wv; acc[5] += c.y * wv; acc[6] += c.z * wv; acc[7] += c.w * wv;
        }
        #pragma unroll
        for (int q = 0; q < ROWS; ++q) part[seg * 512 + r * 8 + q] = acc[q];
    }
    __syncthreads();
    {
        // reduce 4 segs -> dtpre[r*8+row]; 512 values, 256 threads x 2
        int idx = t;
        #pragma unroll
        for (int rep = 0; rep < 2; ++rep, idx += 256) {
            float s = part[idx] + part[512 + idx] + part[1024 + idx] + part[1536 + idx];
            dtpre[idx] = s;
        }
    }
    __syncthreads();

    // ---- phase B: dt[d] = softplus(sum_r dtpre[r]*Wdt2T[r][d] + b_dt[d]); write xdtT ----
    const float4* dp4 = reinterpret_cast<const float4*>(dtpre);
    float2* xTbase = xdtT + (((size_t)b * NCH + ch) * DD) * T_CH;
    #pragma unroll
    for (int dd = 0; dd < 4; ++dd) {
        int d = t + dd * 256;
        float bd = b_dt[d];
        float acc[ROWS];
        #pragma unroll
        for (int q = 0; q < ROWS; ++q) acc[q] = bd;
        const float* wp = Wdt2T + d;
        for (int r = 0; r < 64; ++r) {
            float wv = wp[(size_t)r * 1024];
            float4 p0 = dp4[r * 2];
            float4 p1 = dp4[r * 2 + 1];
            acc[0] += p0.x * wv; acc[1] += p0.y * wv; acc[2] += p0.z * wv; acc[3] += p0.w * wv;
            acc[4] += p1.x * wv; acc[5] += p1.y * wv; acc[6] += p1.z * wv; acc[7] += p1.w * wv;
        }
        float sp[ROWS];
        #pragma unroll
        for (int row = 0; row < ROWS; ++row) sp[row] = softplus_f(acc[row]);
        // 8 consecutive t-slots for this d: 4 float4 stores
        float4* dst4 = (float4*)(xTbase + (size_t)d * T_CH + tt0);
        #pragma unroll
        for (int q = 0; q < 4; ++q)
            dst4[q] = make_float4(xc_reg[dd][2 * q], sp[2 * q],
                                  xc_reg[dd][2 * q + 1], sp[2 * q + 1]);
    }
    // part was last READ before the barrier after phase A reduce; safe to rewrite in C.

    // ---- phase C: B_ssm/C_ssm ----
    {
        int o = t & 31, seg = t >> 5;           // 8 segs x 128 k
        float acc[ROWS];
        #pragma unroll
        for (int q = 0; q < ROWS; ++q) acc[q] = 0.0f;
        const float* wp = WBCT + (size_t)(seg * 128) * 32 + o;
        int kbase = seg * 128;
        for (int i = 0; i < 128; ++i) {
            float wv = wp[(size_t)i * 32];
            float4 a = xr4[(kbase + i) * 2];
            float4 c = xr4[(kbase + i) * 2 + 1];
            acc[0] += a.x * wv; acc[1] += a.y * wv; acc[2] += a.z * wv; acc[3] += a.w * wv;
            acc[4] += c.x * wv; acc[5] += c.y * wv; acc[6] += c.z * wv; acc[7] += c.w * wv;
        }
        #pragma unroll
        for (int q = 0; q < ROWS; ++q) part[seg * 256 + o * 8 + q] = acc[q];
    }
    __syncthreads();
    if (t < 128) {
        int n2 = t >> 3, row = t & 7;   // row-minor so 8-lane groups write 64B contiguous
        float Bv = 0.0f, Cv = 0.0f;
        #pragma unroll
        for (int seg = 0; seg < 8; ++seg) {
            Bv += part[seg * 256 + n2 * 8 + row];
            Cv += part[seg * 256 + (n2 + 16) * 8 + row];
        }
        bcT[(((size_t)b * NCH + ch) * NN + n2) * T_CH + tt0 + row] = make_float2(Bv, Cv);
    }
}

// ---------------- scan: sequential over L, lane = (b, d, n) ----------------
// All inputs stream directly into registers (transposed layouts make each
// lane's stream contiguous); double-buffered at chunk granularity with counted
// vmcnt so the next chunk's 32 loads stay in flight under this chunk's compute.
__device__ __forceinline__ void chunk_load(const float4* __restrict__ xp4,
                                           const float4* __restrict__ bp4,
                                           float4 (&X)[16], float4 (&Bc)[16])
{
    #pragma unroll
    for (int j = 0; j < 16; ++j) X[j] = xp4[j];
    #pragma unroll
    for (int j = 0; j < 16; ++j) Bc[j] = bp4[j];
}

__device__ __forceinline__ void chunk_compute(
    const float4 (&X)[16], const float4 (&Bc)[16],
    float& h, float A2, float Dp, int n, float* __restrict__ yc)
{
    float yr0 = 0.0f, yr1 = 0.0f;
    #pragma unroll
    for (int t = 0; t < T_CH; ++t) {
        const int j = t >> 1, hf = t & 1;
        float xv = hf ? X[j].z : X[j].x;
        float dt = hf ? X[j].w : X[j].y;                 // dt >= 0 (softplus)
        float Bv = hf ? Bc[j].z : Bc[j].x;
        float Cv = hf ? Bc[j].w : Bc[j].y;
        float dtA = fmaxf(dt * A2, -14.426950408889634f); // clip(dt*A,-10,0), log2 domain
        float Abar = fminf(exp2f(dtA), 0.999f);           // clip(exp,0,0.999)
        float tt = med3f(fminf(dt, 1.0f) * Bv, -10.0f, 10.0f);
        h = med3f(fmaf(Abar, h, tt * xv), -100.0f, 100.0f);
        float p = h * Cv;
        p += dpp_ror<0x121>(p);   // 16-lane group all-reduce
        p += dpp_ror<0x122>(p);
        p += dpp_ror<0x124>(p);
        p += dpp_ror<0x128>(p);
        float yv = med3f(fmaf(Dp, xv, p), -50.0f, 50.0f);
        const int ts = t & 15;
        if (t < 16) yr0 = (n == ts) ? yv : yr0;           // branchless capture
        else        yr1 = (n == ts) ? yv : yr1;
    }
    yc[(size_t)n * DD] = yr0;
    yc[(size_t)(16 + n) * DD] = yr1;
}

__global__ __launch_bounds__(64, 1) void scan_kernel(
    const float2* __restrict__ xdtT, const float2* __restrict__ bcT,
    const float* __restrict__ A_log, const float* __restrict__ Dparam,
    float* __restrict__ y)
{
    const int w = blockIdx.x;       // 0..511
    const int b = w >> 8;
    const int dbase = (w & 255) << 2;
    const int lane = threadIdx.x;   // 0..63
    const int n = lane & 15;
    const int dl = lane >> 4;
    const int d = dbase + dl;

    // A2 = A * log2(e) so the per-step exp is a bare v_exp_f32 (2^x)
    const float A2 = -__expf(A_log[d * NN + n]) * 1.4426950408889634f;
    const float Dp = Dparam[d];

    // per-lane stream bases (chunk 0); chunk strides in float4 units
    const float4* xp = (const float4*)(xdtT + ((size_t)b * NCH * DD + d) * T_CH);
    const float4* bp = (const float4*)(bcT + ((size_t)b * NCH * NN + n) * T_CH);
    const size_t XSTR = (size_t)DD * T_CH / 2;   // 16384 float4 per chunk
    const size_t BSTR = (size_t)NN * T_CH / 2;   // 256 float4 per chunk

    float* yb = y + (size_t)b * LL * DD + dbase + dl;

    float4 XA[16], BA[16], XB[16], BB2[16];
    float h = 0.0f;

    // prologue: chunks 0 and 1 in flight; wait for chunk 0 (32 remain)
    chunk_load(xp, bp, XA, BA);
    chunk_load(xp + XSTR, bp + BSTR, XB, BB2);
    asm volatile("s_waitcnt vmcnt(32)" ::: "memory");
    chunk_compute(XA, BA, h, A2, Dp, n, yb);

    // steady state: c = 2,4,...,126. Queue at each wait (in-order retirement):
    // [L_prev(32), S(2), L_new(32)] -> vmcnt(34) retires exactly L_prev.
    #pragma unroll 1
    for (int c = 2; c <= NCH - 2; c += 2) {
        chunk_load(xp + (size_t)c * XSTR, bp + (size_t)c * BSTR, XA, BA);
        asm volatile("s_waitcnt vmcnt(34)" ::: "memory");
        chunk_compute(XB, BB2, h, A2, Dp, n, yb + (size_t)(c - 1) * T_CH * DD);
        chunk_load(xp + (size_t)(c + 1) * XSTR, bp + (size_t)(c + 1) * BSTR, XB, BB2);
        asm volatile("s_waitcnt vmcnt(34)" ::: "memory");
        chunk_compute(XA, BA, h, A2, Dp, n, yb + (size_t)c * T_CH * DD);
    }

    // tail: chunk 127 (loaded in last iteration into XB/BB2)
    asm volatile("s_waitcnt vmcnt(2)" ::: "memory");
    chunk_compute(XB, BB2, h, A2, Dp, n, yb + (size_t)(NCH - 1) * T_CH * DD);
}

// ---------------- launch ----------------
extern "C" void kernel_launch(void* const* d_in, const int* in_sizes, int n_in,
                              void* d_out, int out_size, void* d_ws, size_t ws_size,
                              hipStream_t stream) {
    const float* x      = (const float*)d_in[0];
    const float* A_log  = (const float*)d_in[1];
    const float* Dparam = (const float*)d_in[2];
    const float* W_dt1  = (const float*)d_in[3];
    const float* W_dt2  = (const float*)d_in[4];
    const float* b_dt   = (const float*)d_in[5];
    const float* W_B    = (const float*)d_in[6];
    const float* W_C    = (const float*)d_in[7];
    const float* conv_w = (const float*)d_in[8];
    const float* conv_b = (const float*)d_in[9];
    float* y = (float*)d_out;

    float* ws = (float*)d_ws;
    // layout (floats): xdtT 16M | bcT 256K | Wdt1T 64K | Wdt2T 64K | WBCT 32K
    float2* xdtT = (float2*)ws;
    float2* bcT  = (float2*)(ws + (size_t)2 * BB * LL * DD);
    float* Wdt1T = ws + (size_t)2 * BB * LL * DD + (size_t)2 * BB * LL * NN;
    float* Wdt2T = Wdt1T + 65536;
    float* WBCT  = Wdt2T + 65536;

    prep_kernel<<<256, 256, 0, stream>>>(W_dt1, W_dt2, W_B, W_C, Wdt1T, Wdt2T, WBCT);
    proj_kernel<<<BB * (LL / ROWS), 256, 0, stream>>>(x, conv_w, conv_b, Wdt1T, Wdt2T,
                                                      b_dt, WBCT, xdtT, bcT);
    scan_kernel<<<BB * (DD / 4), 64, 0, stream>>>(xdtT, bcT, A_log, Dparam, y);
}

// Round 7
// 454.913 us; speedup vs baseline: 3.3476x; 1.0813x over previous
//
#include <hip/hip_runtime.h>
#include <hip/hip_bf16.h>

// Problem dims (fixed by setup_inputs)
#define BB 2
#define LL 4096
#define DD 1024
#define NN 16
#define RR 64
#define KK 4
#define ROWS 8   // rows (l) per proj block == one scan granule

#define TG 8               // granule (timesteps) per register buffer
#define NG (LL / TG)       // 512 granules

// ---------------- helpers ----------------

__device__ __forceinline__ float med3f(float x, float lo, float hi) {
    return __builtin_amdgcn_fmed3f(x, lo, hi);
}

template<int CTRL>
__device__ __forceinline__ float dpp_ror(float v) {
    int r = __builtin_amdgcn_update_dpp(0, __builtin_bit_cast(int, v), CTRL, 0xf, 0xf, true);
    return __builtin_bit_cast(float, r);
}

__device__ __forceinline__ float silu_f(float z) {
    float e = __expf(-z);
    return z * __builtin_amdgcn_rcpf(1.0f + e);
}

__device__ __forceinline__ float softplus_f(float z) {
    float e = __expf(-fabsf(z));
    return fmaxf(z, 0.0f) + __logf(1.0f + e);
}

// ---------------- prep: weight transposes ----------------
__global__ __launch_bounds__(256) void prep_kernel(
    const float* __restrict__ Wdt1, const float* __restrict__ Wdt2,
    const float* __restrict__ WB, const float* __restrict__ WC,
    float* __restrict__ Wdt1T, float* __restrict__ Wdt2T, float* __restrict__ WBCT)
{
    int i = blockIdx.x * 256 + threadIdx.x;   // up to 65536
    if (i < 65536) {
        int k = i >> 6, r = i & 63;
        Wdt1T[i] = Wdt1[r * 1024 + k];
    }
    if (i < 65536) {
        int r = i >> 10, d = i & 1023;
        Wdt2T[i] = Wdt2[d * 64 + r];
    }
    if (i < 32768) {
        int k = i >> 5, o = i & 31;
        WBCT[i] = (o < 16) ? WB[o * 1024 + k] : WC[(o - 16) * 1024 + k];
    }
}

// ---------------- proj: conv + silu + dt/B/C projections ----------------
// Scan-native granule layouts (granule g = l/8, t = l%8):
//   xdtT[((b*NG + g)*DD + d)*TG + t] = {x_conv, dt}
//   bcT [((b*NG + g)*NN + n)*TG + t] = {B, C}
__global__ __launch_bounds__(256) void proj_kernel(
    const float* __restrict__ x,
    const float* __restrict__ conv_w, const float* __restrict__ conv_b,
    const float* __restrict__ Wdt1T, const float* __restrict__ Wdt2T,
    const float* __restrict__ b_dt, const float* __restrict__ WBCT,
    float2* __restrict__ xdtT, float2* __restrict__ bcT)
{
    __shared__ alignas(16) float xc8[1024 * ROWS];   // [d][row], 32KB
    __shared__ alignas(16) float part[2048];         // 8KB, reused A/C
    __shared__ alignas(16) float dtpre[64 * ROWS];   // [r][row], 2KB

    const int t = threadIdx.x;
    const int blk = blockIdx.x;             // 0..1023
    const int b = blk >> 9;                 // 512 blocks per batch
    const int l0 = (blk & 511) << 3;        // row base
    const int gg = l0 >> 3;                 // granule index (== blk&511)
    const float* xb = x + (size_t)b * LL * DD;

    // ---- conv + silu, 4 d's per thread, 8 rows each ----
    float xc_reg[4][ROWS];
    #pragma unroll
    for (int dd = 0; dd < 4; ++dd) {
        int d = t + dd * 256;
        float4 w4 = reinterpret_cast<const float4*>(conv_w)[d];
        float cb = conv_b[d];
        float xv[ROWS + 3];
        #pragma unroll
        for (int j = 0; j < ROWS + 3; ++j) {
            int l = l0 - 3 + j;
            xv[j] = (l >= 0) ? xb[(size_t)l * DD + d] : 0.0f;
        }
        #pragma unroll
        for (int r = 0; r < ROWS; ++r) {
            float s = cb + xv[r] * w4.x + xv[r + 1] * w4.y + xv[r + 2] * w4.z + xv[r + 3] * w4.w;
            xc_reg[dd][r] = silu_f(s);
        }
        float4 lo = make_float4(xc_reg[dd][0], xc_reg[dd][1], xc_reg[dd][2], xc_reg[dd][3]);
        float4 hi = make_float4(xc_reg[dd][4], xc_reg[dd][5], xc_reg[dd][6], xc_reg[dd][7]);
        reinterpret_cast<float4*>(&xc8[d * ROWS])[0] = lo;
        reinterpret_cast<float4*>(&xc8[d * ROWS])[1] = hi;
    }
    __syncthreads();

    const float4* xr4 = reinterpret_cast<const float4*>(xc8);

    // ---- phase A: dt_pre[r] = sum_k xc[k] * Wdt1T[k][r] ----
    {
        int r = t & 63, seg = t >> 6;           // 4 segs x 256 k
        float acc[ROWS];
        #pragma unroll
        for (int q = 0; q < ROWS; ++q) acc[q] = 0.0f;
        const float* wp = Wdt1T + (size_t)(seg * 256) * 64 + r;
        int kbase = seg * 256;
        for (int i = 0; i < 256; ++i) {
            float wv = wp[(size_t)i * 64];
            float4 a = xr4[(kbase + i) * 2];
            float4 c = xr4[(kbase + i) * 2 + 1];
            acc[0] += a.x * wv; acc[1] += a.y * wv; acc[2] += a.z * wv; acc[3] += a.w * wv;
            acc[4] += c.x * wv; acc[5] += c.y * wv; acc[6] += c.z * wv; acc[7] += c.w * wv;
        }
        #pragma unroll
        for (int q = 0; q < ROWS; ++q) part[seg * 512 + r * 8 + q] = acc[q];
    }
    __syncthreads();
    {
        int idx = t;
        #pragma unroll
        for (int rep = 0; rep < 2; ++rep, idx += 256) {
            float s = part[idx] + part[512 + idx] + part[1024 + idx] + part[1536 + idx];
            dtpre[idx] = s;
        }
    }
    __syncthreads();

    // ---- phase B: dt[d] = softplus(GEMV + b_dt); write xdtT granule ----
    const float4* dp4 = reinterpret_cast<const float4*>(dtpre);
    float2* xTbase = xdtT + ((size_t)b * NG + gg) * DD * TG;
    #pragma unroll
    for (int dd = 0; dd < 4; ++dd) {
        int d = t + dd * 256;
        float bd = b_dt[d];
        float acc[ROWS];
        #pragma unroll
        for (int q = 0; q < ROWS; ++q) acc[q] = bd;
        const float* wp = Wdt2T + d;
        for (int r = 0; r < 64; ++r) {
            float wv = wp[(size_t)r * 1024];
            float4 p0 = dp4[r * 2];
            float4 p1 = dp4[r * 2 + 1];
            acc[0] += p0.x * wv; acc[1] += p0.y * wv; acc[2] += p0.z * wv; acc[3] += p0.w * wv;
            acc[4] += p1.x * wv; acc[5] += p1.y * wv; acc[6] += p1.z * wv; acc[7] += p1.w * wv;
        }
        float sp[ROWS];
        #pragma unroll
        for (int row = 0; row < ROWS; ++row) sp[row] = softplus_f(acc[row]);
        // lane d's 8 t-slots: 64B contiguous; lanes contiguous across d
        float4* dst4 = (float4*)(xTbase + (size_t)d * TG);
        #pragma unroll
        for (int q = 0; q < 4; ++q)
            dst4[q] = make_float4(xc_reg[dd][2 * q], sp[2 * q],
                                  xc_reg[dd][2 * q + 1], sp[2 * q + 1]);
    }

    // ---- phase C: B_ssm/C_ssm ----
    {
        int o = t & 31, seg = t >> 5;           // 8 segs x 128 k
        float acc[ROWS];
        #pragma unroll
        for (int q = 0; q < ROWS; ++q) acc[q] = 0.0f;
        const float* wp = WBCT + (size_t)(seg * 128) * 32 + o;
        int kbase = seg * 128;
        for (int i = 0; i < 128; ++i) {
            float wv = wp[(size_t)i * 32];
            float4 a = xr4[(kbase + i) * 2];
            float4 c = xr4[(kbase + i) * 2 + 1];
            acc[0] += a.x * wv; acc[1] += a.y * wv; acc[2] += a.z * wv; acc[3] += a.w * wv;
            acc[4] += c.x * wv; acc[5] += c.y * wv; acc[6] += c.z * wv; acc[7] += c.w * wv;
        }
        #pragma unroll
        for (int q = 0; q < ROWS; ++q) part[seg * 256 + o * 8 + q] = acc[q];
    }
    __syncthreads();
    if (t < 128) {
        int n2 = t >> 3, row = t & 7;   // consecutive t -> contiguous output
        float Bv = 0.0f, Cv = 0.0f;
        #pragma unroll
        for (int seg = 0; seg < 8; ++seg) {
            Bv += part[seg * 256 + n2 * 8 + row];
            Cv += part[seg * 256 + (n2 + 16) * 8 + row];
        }
        bcT[(((size_t)b * NG + gg) * NN + n2) * TG + row] = make_float2(Bv, Cv);
    }
}

// ---------------- scan ----------------
// Ring of 4 named 8-step granule buffers, 3-deep prefetch, counted vmcnt.
// Per granule: pass1 (parallel Abar/u/Dx) then pass2 (tight serial h-chain).
struct Gran { float4 X[4]; float4 B[4]; };

__device__ __forceinline__ void gload(Gran& G, const float4* __restrict__ xq,
                                      const float4* __restrict__ bq) {
    #pragma unroll
    for (int j = 0; j < 4; ++j) G.X[j] = xq[j];
    #pragma unroll
    for (int j = 0; j < 4; ++j) G.B[j] = bq[j];
}

template<int PAR>
__device__ __forceinline__ void consume(const Gran& G, float& h, float& yr,
                                        float A2, float Dp, int n) {
    float a[TG], u[TG], Dx[TG];
    #pragma unroll
    for (int t = 0; t < TG; ++t) {            // pass 1: independent across t
        const int j = t >> 1; const bool hf = t & 1;
        float xv = hf ? G.X[j].z : G.X[j].x;
        float dt = hf ? G.X[j].w : G.X[j].y;  // dt >= 0 (softplus)
        a[t] = fminf(__builtin_amdgcn_exp2f(fmaxf(dt * A2, -14.426950408889634f)), 0.999f);
        u[t] = med3f(fminf(dt, 1.0f) * (hf ? G.B[j].z : G.B[j].x), -10.0f, 10.0f) * xv;
        Dx[t] = Dp * xv;
    }
    #pragma unroll
    for (int t = 0; t < TG; ++t) {            // pass 2: serial h-chain + reduce
        const int j = t >> 1; const bool hf = t & 1;
        float Cv = hf ? G.B[j].w : G.B[j].y;
        h = med3f(fmaf(a[t], h, u[t]), -100.0f, 100.0f);
        float p = h * Cv;
        p += dpp_ror<0x121>(p);
        p += dpp_ror<0x122>(p);
        p += dpp_ror<0x124>(p);
        p += dpp_ror<0x128>(p);
        float yv = med3f(p + Dx[t], -50.0f, 50.0f);
        yr = (n == PAR * TG + t) ? yv : yr;   // branchless capture
    }
}

#define SCAN_ITER(RING, PAR, DO_STORE, LG)                                 \
    asm volatile("s_waitcnt vmcnt(24)" ::: "memory");                      \
    consume<PAR>(RING, h, yr, A2, Dp, n);                                  \
    if (DO_STORE) { *yq = yr; yq += 16 * DD; }                             \
    gload(RING, xq + (size_t)(LG) * 4096, bq + (size_t)(LG) * 64);

__global__ __launch_bounds__(64, 1) void scan_kernel(
    const float2* __restrict__ xdtT, const float2* __restrict__ bcT,
    const float* __restrict__ A_log, const float* __restrict__ Dparam,
    float* __restrict__ y)
{
    const int w = blockIdx.x;       // 0..511
    const int b = w >> 8;
    const int dbase = (w & 255) << 2;
    const int lane = threadIdx.x;   // 0..63
    const int n = lane & 15;
    const int dl = lane >> 4;
    const int d = dbase + dl;

    const float A2 = -__expf(A_log[d * NN + n]) * 1.4426950408889634f;
    const float Dp = Dparam[d];

    // per-lane granule-0 stream bases; granule strides: X 4096, B 64 (float4)
    const float4* xq = (const float4*)(xdtT + ((size_t)b * NG * DD + d) * TG);
    const float4* bq = (const float4*)(bcT + ((size_t)b * NG * NN + n) * TG);
    // lane (dl,n) stores y[pair*16 + n][dbase+dl]
    float* yq = y + ((size_t)b * LL + n) * DD + dbase + dl;

    Gran r0, r1, r2, r3;
    float h = 0.0f, yr = 0.0f;

    // prologue: granules 0..3 in flight
    gload(r0, xq, bq);
    gload(r1, xq + 4096, bq + 64);
    gload(r2, xq + 2 * 4096, bq + 2 * 64);
    gload(r3, xq + 3 * 4096, bq + 3 * 64);

    // steady: 127 blocks x 4 granules; consumes 0..507, loads 4..511
    #pragma unroll 1
    for (int blk = 0; blk < 127; ++blk) {
        const int g4 = blk * 4;
        SCAN_ITER(r0, 0, false, g4 + 4)
        SCAN_ITER(r1, 1, true,  g4 + 5)
        SCAN_ITER(r2, 0, false, g4 + 6)
        SCAN_ITER(r3, 1, true,  g4 + 7)
    }

    // tail: granules 508..511
    asm volatile("s_waitcnt vmcnt(24)" ::: "memory");
    consume<0>(r0, h, yr, A2, Dp, n);
    asm volatile("s_waitcnt vmcnt(16)" ::: "memory");
    consume<1>(r1, h, yr, A2, Dp, n);
    *yq = yr; yq += 16 * DD;
    asm volatile("s_waitcnt vmcnt(8)" ::: "memory");
    consume<0>(r2, h, yr, A2, Dp, n);
    asm volatile("s_waitcnt vmcnt(0)" ::: "memory");
    consume<1>(r3, h, yr, A2, Dp, n);
    *yq = yr;
}

// ---------------- launch ----------------
extern "C" void kernel_launch(void* const* d_in, const int* in_sizes, int n_in,
                              void* d_out, int out_size, void* d_ws, size_t ws_size,
                              hipStream_t stream) {
    const float* x      = (const float*)d_in[0];
    const float* A_log  = (const float*)d_in[1];
    const float* Dparam = (const float*)d_in[2];
    const float* W_dt1  = (const float*)d_in[3];
    const float* W_dt2  = (const float*)d_in[4];
    const float* b_dt   = (const float*)d_in[5];
    const float* W_B    = (const float*)d_in[6];
    const float* W_C    = (const float*)d_in[7];
    const float* conv_w = (const float*)d_in[8];
    const float* conv_b = (const float*)d_in[9];
    float* y = (float*)d_out;

    float* ws = (float*)d_ws;
    // layout (floats): xdtT 16M | bcT 256K | Wdt1T 64K | Wdt2T 64K | WBCT 32K
    float2* xdtT = (float2*)ws;
    float2* bcT  = (float2*)(ws + (size_t)2 * BB * LL * DD);
    float* Wdt1T = ws + (size_t)2 * BB * LL * DD + (size_t)2 * BB * LL * NN;
    float* Wdt2T = Wdt1T + 65536;
    float* WBCT  = Wdt2T + 65536;

    prep_kernel<<<256, 256, 0, stream>>>(W_dt1, W_dt2, W_B, W_C, Wdt1T, Wdt2T, WBCT);
    proj_kernel<<<BB * (LL / ROWS), 256, 0, stream>>>(x, conv_w, conv_b, Wdt1T, Wdt2T,
                                                      b_dt, WBCT, xdtT, bcT);
    scan_kernel<<<BB * (DD / 4), 64, 0, stream>>>(xdtT, bcT, A_log, Dparam, y);
}

// Round 8
// 451.801 us; speedup vs baseline: 3.3707x; 1.0069x over previous
//
#include <hip/hip_runtime.h>
#include <hip/hip_bf16.h>

// Problem dims (fixed by setup_inputs)
#define BB 2
#define LL 4096
#define DD 1024
#define NN 16
#define RR 64
#define KK 4
#define ROWS 8   // rows (l) per proj block == one scan granule

#define TG 8               // granule (timesteps) per register buffer
#define NG (LL / TG)       // 512 granules
#define KC 4               // scan chunks (parallel-replay decomposition)
#define GPC (NG / KC)      // 128 granules per chunk

// ---------------- helpers ----------------

__device__ __forceinline__ float med3f(float x, float lo, float hi) {
    return __builtin_amdgcn_fmed3f(x, lo, hi);
}

template<int CTRL>
__device__ __forceinline__ float dpp_ror(float v) {
    int r = __builtin_amdgcn_update_dpp(0, __builtin_bit_cast(int, v), CTRL, 0xf, 0xf, true);
    return __builtin_bit_cast(float, r);
}

__device__ __forceinline__ float silu_f(float z) {
    float e = __expf(-z);
    return z * __builtin_amdgcn_rcpf(1.0f + e);
}

__device__ __forceinline__ float softplus_f(float z) {
    float e = __expf(-fabsf(z));
    return fmaxf(z, 0.0f) + __logf(1.0f + e);
}

// ---------------- prep: weight transposes ----------------
__global__ __launch_bounds__(256) void prep_kernel(
    const float* __restrict__ Wdt1, const float* __restrict__ Wdt2,
    const float* __restrict__ WB, const float* __restrict__ WC,
    float* __restrict__ Wdt1T, float* __restrict__ Wdt2T, float* __restrict__ WBCT)
{
    int i = blockIdx.x * 256 + threadIdx.x;   // up to 65536
    if (i < 65536) {
        int k = i >> 6, r = i & 63;
        Wdt1T[i] = Wdt1[r * 1024 + k];
    }
    if (i < 65536) {
        int r = i >> 10, d = i & 1023;
        Wdt2T[i] = Wdt2[d * 64 + r];
    }
    if (i < 32768) {
        int k = i >> 5, o = i & 31;
        WBCT[i] = (o < 16) ? WB[o * 1024 + k] : WC[(o - 16) * 1024 + k];
    }
}

// ---------------- proj: conv + silu + dt/B/C projections ----------------
// Scan-native granule layouts (granule g = l/8, t = l%8):
//   xdtT[((b*NG + g)*DD + d)*TG + t] = {x_conv, dt}
//   bcT [((b*NG + g)*NN + n)*TG + t] = {B, C}
// xdtT granule (64KB) is staged through LDS in two 32KB halves so the
// global stores are fully coalesced.
__global__ __launch_bounds__(256) void proj_kernel(
    const float* __restrict__ x,
    const float* __restrict__ conv_w, const float* __restrict__ conv_b,
    const float* __restrict__ Wdt1T, const float* __restrict__ Wdt2T,
    const float* __restrict__ b_dt, const float* __restrict__ WBCT,
    float2* __restrict__ xdtT, float2* __restrict__ bcT)
{
    __shared__ alignas(16) float xc8[1024 * ROWS];   // [d][row] 32KB; reused as stage buf
    __shared__ alignas(16) float part[2048];         // 8KB, reused A/C
    __shared__ alignas(16) float dtpre[64 * ROWS];   // [r][row], 2KB

    const int t = threadIdx.x;
    const int blk = blockIdx.x;             // 0..1023
    const int b = blk >> 9;                 // 512 blocks per batch
    const int l0 = (blk & 511) << 3;        // row base
    const int gg = l0 >> 3;                 // granule index
    const float* xb = x + (size_t)b * LL * DD;

    // ---- conv + silu, 4 d's per thread, 8 rows each ----
    float xc_reg[4][ROWS];
    #pragma unroll
    for (int dd = 0; dd < 4; ++dd) {
        int d = t + dd * 256;
        float4 w4 = reinterpret_cast<const float4*>(conv_w)[d];
        float cb = conv_b[d];
        float xv[ROWS + 3];
        #pragma unroll
        for (int j = 0; j < ROWS + 3; ++j) {
            int l = l0 - 3 + j;
            xv[j] = (l >= 0) ? xb[(size_t)l * DD + d] : 0.0f;
        }
        #pragma unroll
        for (int r = 0; r < ROWS; ++r) {
            float s = cb + xv[r] * w4.x + xv[r + 1] * w4.y + xv[r + 2] * w4.z + xv[r + 3] * w4.w;
            xc_reg[dd][r] = silu_f(s);
        }
        float4 lo = make_float4(xc_reg[dd][0], xc_reg[dd][1], xc_reg[dd][2], xc_reg[dd][3]);
        float4 hi = make_float4(xc_reg[dd][4], xc_reg[dd][5], xc_reg[dd][6], xc_reg[dd][7]);
        reinterpret_cast<float4*>(&xc8[d * ROWS])[0] = lo;
        reinterpret_cast<float4*>(&xc8[d * ROWS])[1] = hi;
    }
    __syncthreads();

    const float4* xr4 = reinterpret_cast<const float4*>(xc8);

    // ---- phase A: dt_pre[r] = sum_k xc[k] * Wdt1T[k][r] ----
    {
        int r = t & 63, seg = t >> 6;           // 4 segs x 256 k
        float acc[ROWS];
        #pragma unroll
        for (int q = 0; q < ROWS; ++q) acc[q] = 0.0f;
        const float* wp = Wdt1T + (size_t)(seg * 256) * 64 + r;
        int kbase = seg * 256;
        for (int i = 0; i < 256; ++i) {
            float wv = wp[(size_t)i * 64];
            float4 a = xr4[(kbase + i) * 2];
            float4 c = xr4[(kbase + i) * 2 + 1];
            acc[0] += a.x * wv; acc[1] += a.y * wv; acc[2] += a.z * wv; acc[3] += a.w * wv;
            acc[4] += c.x * wv; acc[5] += c.y * wv; acc[6] += c.z * wv; acc[7] += c.w * wv;
        }
        #pragma unroll
        for (int q = 0; q < ROWS; ++q) part[seg * 512 + r * 8 + q] = acc[q];
    }
    __syncthreads();
    {
        int idx = t;
        #pragma unroll
        for (int rep = 0; rep < 2; ++rep, idx += 256) {
            float s = part[idx] + part[512 + idx] + part[1024 + idx] + part[1536 + idx];
            dtpre[idx] = s;
        }
    }
    __syncthreads();

    // ---- phase C: B_ssm/C_ssm (runs BEFORE B so xc8 can be reused) ----
    {
        int o = t & 31, seg = t >> 5;           // 8 segs x 128 k
        float acc[ROWS];
        #pragma unroll
        for (int q = 0; q < ROWS; ++q) acc[q] = 0.0f;
        const float* wp = WBCT + (size_t)(seg * 128) * 32 + o;
        int kbase = seg * 128;
        for (int i = 0; i < 128; ++i) {
            float wv = wp[(size_t)i * 32];
            float4 a = xr4[(kbase + i) * 2];
            float4 c = xr4[(kbase + i) * 2 + 1];
            acc[0] += a.x * wv; acc[1] += a.y * wv; acc[2] += a.z * wv; acc[3] += a.w * wv;
            acc[4] += c.x * wv; acc[5] += c.y * wv; acc[6] += c.z * wv; acc[7] += c.w * wv;
        }
        #pragma unroll
        for (int q = 0; q < ROWS; ++q) part[seg * 256 + o * 8 + q] = acc[q];
    }
    __syncthreads();   // after this barrier xc8's conv data has no more readers
    if (t < 128) {
        int n2 = t >> 3, row = t & 7;   // offset = t*8B -> contiguous 1KB store
        float Bv = 0.0f, Cv = 0.0f;
        #pragma unroll
        for (int seg = 0; seg < 8; ++seg) {
            Bv += part[seg * 256 + n2 * 8 + row];
            Cv += part[seg * 256 + (n2 + 16) * 8 + row];
        }
        bcT[(((size_t)b * NG + gg) * NN + n2) * TG + row] = make_float2(Bv, Cv);
    }

    // ---- phase B: dt = softplus(GEMV + b_dt); staged coalesced xdtT store ----
    const float4* dp4 = reinterpret_cast<const float4*>(dtpre);
    float4* xc84 = reinterpret_cast<float4*>(xc8);
    float4* xT4 = (float4*)(xdtT + ((size_t)b * NG + gg) * DD * TG);

    // dd = 0,1: GEMV + stage into xc8 [d-local][t] (d 0..511)
    #pragma unroll
    for (int dd = 0; dd < 2; ++dd) {
        int d = t + dd * 256;
        float bd = b_dt[d];
        float acc[ROWS];
        #pragma unroll
        for (int q = 0; q < ROWS; ++q) acc[q] = bd;
        const float* wp = Wdt2T + d;
        for (int r = 0; r < 64; ++r) {
            float wv = wp[(size_t)r * 1024];
            float4 p0 = dp4[r * 2];
            float4 p1 = dp4[r * 2 + 1];
            acc[0] += p0.x * wv; acc[1] += p0.y * wv; acc[2] += p0.z * wv; acc[3] += p0.w * wv;
            acc[4] += p1.x * wv; acc[5] += p1.y * wv; acc[6] += p1.z * wv; acc[7] += p1.w * wv;
        }
        float4* s4 = xc84 + (size_t)d * 4;
        #pragma unroll
        for (int q = 0; q < 4; ++q)
            s4[q] = make_float4(xc_reg[dd][2 * q], softplus_f(acc[2 * q]),
                                xc_reg[dd][2 * q + 1], softplus_f(acc[2 * q + 1]));
    }
    // dd = 2,3: GEMV to registers (staged after flush1)
    float sp23[2][ROWS];
    #pragma unroll
    for (int dd = 2; dd < 4; ++dd) {
        int d = t + dd * 256;
        float bd = b_dt[d];
        float acc[ROWS];
        #pragma unroll
        for (int q = 0; q < ROWS; ++q) acc[q] = bd;
        const float* wp = Wdt2T + d;
        for (int r = 0; r < 64; ++r) {
            float wv = wp[(size_t)r * 1024];
            float4 p0 = dp4[r * 2];
            float4 p1 = dp4[r * 2 + 1];
            acc[0] += p0.x * wv; acc[1] += p0.y * wv; acc[2] += p0.z * wv; acc[3] += p0.w * wv;
            acc[4] += p1.x * wv; acc[5] += p1.y * wv; acc[6] += p1.z * wv; acc[7] += p1.w * wv;
        }
        #pragma unroll
        for (int q = 0; q < ROWS; ++q) sp23[dd - 2][q] = softplus_f(acc[q]);
    }
    __syncthreads();   // stage1 visible
    #pragma unroll
    for (int j = 0; j < 8; ++j)       // flush half 1: d 0..511, coalesced
        xT4[j * 256 + t] = xc84[j * 256 + t];
    __syncthreads();   // flush1 reads done
    #pragma unroll
    for (int dd = 0; dd < 2; ++dd) {  // stage d 512..1023 at local offset
        float4* s4 = xc84 + (size_t)(t + dd * 256) * 4;
        #pragma unroll
        for (int q = 0; q < 4; ++q)
            s4[q] = make_float4(xc_reg[dd + 2][2 * q], sp23[dd][2 * q],
                                xc_reg[dd + 2][2 * q + 1], sp23[dd][2 * q + 1]);
    }
    __syncthreads();   // stage2 visible
    #pragma unroll
    for (int j = 0; j < 8; ++j)       // flush half 2
        xT4[2048 + j * 256 + t] = xc84[j * 256 + t];
}

// ---------------- scan ----------------
// KC-chunk decomposition: wave k bit-exactly replays the h-recurrence (no y)
// over granules [0, k*GPC), then runs the full scan over its own chunk.
// 2048 waves -> 8/CU -> 2/SIMD: all SIMDs busy, co-resident waves hide latency.
struct Gran { float4 X[4]; float4 B[4]; };

__device__ __forceinline__ void gload(Gran& G, const float4* __restrict__ xq,
                                      const float4* __restrict__ bq) {
    #pragma unroll
    for (int j = 0; j < 4; ++j) G.X[j] = xq[j];
    #pragma unroll
    for (int j = 0; j < 4; ++j) G.B[j] = bq[j];
}

// full consume: h-chain + y (branchless capture)
template<int PAR>
__device__ __forceinline__ void consume(const Gran& G, float& h, float& yr,
                                        float A2, float Dp, int n) {
    float a[TG], u[TG], Dx[TG];
    #pragma unroll
    for (int t = 0; t < TG; ++t) {
        const int j = t >> 1; const bool hf = t & 1;
        float xv = hf ? G.X[j].z : G.X[j].x;
        float dt = hf ? G.X[j].w : G.X[j].y;
        a[t] = fminf(__builtin_amdgcn_exp2f(fmaxf(dt * A2, -14.426950408889634f)), 0.999f);
        u[t] = med3f(fminf(dt, 1.0f) * (hf ? G.B[j].z : G.B[j].x), -10.0f, 10.0f) * xv;
        Dx[t] = Dp * xv;
    }
    #pragma unroll
    for (int t = 0; t < TG; ++t) {
        const int j = t >> 1; const bool hf = t & 1;
        float Cv = hf ? G.B[j].w : G.B[j].y;
        h = med3f(fmaf(a[t], h, u[t]), -100.0f, 100.0f);
        float p = h * Cv;
        p += dpp_ror<0x121>(p);
        p += dpp_ror<0x122>(p);
        p += dpp_ror<0x124>(p);
        p += dpp_ror<0x128>(p);
        float yv = med3f(p + Dx[t], -50.0f, 50.0f);
        yr = (n == PAR * TG + t) ? yv : yr;
    }
}

// h-only consume (phase-1 replay): identical recurrence, no y path
__device__ __forceinline__ void consume_h(const Gran& G, float& h, float A2) {
    float a[TG], u[TG];
    #pragma unroll
    for (int t = 0; t < TG; ++t) {
        const int j = t >> 1; const bool hf = t & 1;
        float xv = hf ? G.X[j].z : G.X[j].x;
        float dt = hf ? G.X[j].w : G.X[j].y;
        a[t] = fminf(__builtin_amdgcn_exp2f(fmaxf(dt * A2, -14.426950408889634f)), 0.999f);
        u[t] = med3f(fminf(dt, 1.0f) * (hf ? G.B[j].z : G.B[j].x), -10.0f, 10.0f) * xv;
    }
    #pragma unroll
    for (int t = 0; t < TG; ++t)
        h = med3f(fmaf(a[t], h, u[t]), -100.0f, 100.0f);
}

#define SCAN_ITER(RING, PAR, DO_STORE, LG)                                 \
    asm volatile("s_waitcnt vmcnt(24)" ::: "memory");                      \
    consume<PAR>(RING, h, yr, A2, Dp, n);                                  \
    if (DO_STORE) { *yq = yr; yq += 16 * DD; }                             \
    gload(RING, xq + (size_t)(LG) * 4096, bq + (size_t)(LG) * 64);

#define H_ITER(RING, LG)                                                   \
    asm volatile("s_waitcnt vmcnt(24)" ::: "memory");                      \
    consume_h(RING, h, A2);                                                \
    gload(RING, xq + (size_t)(LG) * 4096, bq + (size_t)(LG) * 64);

__global__ __launch_bounds__(64, 2) void scan_kernel(
    const float2* __restrict__ xdtT, const float2* __restrict__ bcT,
    const float* __restrict__ A_log, const float* __restrict__ Dparam,
    float* __restrict__ y)
{
    const int w = blockIdx.x;            // 0..2047
    const int dgrp = w & 255;
    const int k = (w >> 8) & (KC - 1);
    const int b = w >> 10;
    const int dbase = dgrp << 2;
    const int lane = threadIdx.x;        // 0..63
    const int n = lane & 15;
    const int dl = lane >> 4;
    const int d = dbase + dl;

    const float A2 = -__expf(A_log[d * NN + n]) * 1.4426950408889634f;
    const float Dp = Dparam[d];

    // per-lane granule-0 stream bases; granule strides: X 4096, B 64 (float4)
    const float4* xq = (const float4*)(xdtT + ((size_t)b * NG * DD + d) * TG);
    const float4* bq = (const float4*)(bcT + ((size_t)b * NG * NN + n) * TG);
    // wave k's y region starts at l = k*GPC*TG
    float* yq = y + ((size_t)b * LL + k * GPC * TG + n) * DD + dbase + dl;

    const int p1 = k * GPC;              // phase-1 granules (multiple of 4)
    const int nb = (p1 + GPC) >> 2;      // 4-granule blocks incl. tail

    Gran r0, r1, r2, r3;
    float h = 0.0f, yr = 0.0f;

    gload(r0, xq, bq);
    gload(r1, xq + 4096, bq + 64);
    gload(r2, xq + 2 * 4096, bq + 2 * 64);
    gload(r3, xq + 3 * 4096, bq + 3 * 64);

    #pragma unroll 1
    for (int blk = 0; blk < nb - 1; ++blk) {
        const int g4 = blk * 4;
        if (g4 < p1) {                   // phase 1: h-only replay
            H_ITER(r0, g4 + 4)
            H_ITER(r1, g4 + 5)
            H_ITER(r2, g4 + 6)
            H_ITER(r3, g4 + 7)
        } else {                         // phase 2: full scan with y
            SCAN_ITER(r0, 0, false, g4 + 4)
            SCAN_ITER(r1, 1, true,  g4 + 5)
            SCAN_ITER(r2, 0, false, g4 + 6)
            SCAN_ITER(r3, 1, true,  g4 + 7)
        }
    }

    // tail: last 4 granules of this wave's chunk (always full-consume)
    asm volatile("s_waitcnt vmcnt(24)" ::: "memory");
    consume<0>(r0, h, yr, A2, Dp, n);
    asm volatile("s_waitcnt vmcnt(16)" ::: "memory");
    consume<1>(r1, h, yr, A2, Dp, n);
    *yq = yr; yq += 16 * DD;
    asm volatile("s_waitcnt vmcnt(8)" ::: "memory");
    consume<0>(r2, h, yr, A2, Dp, n);
    asm volatile("s_waitcnt vmcnt(0)" ::: "memory");
    consume<1>(r3, h, yr, A2, Dp, n);
    *yq = yr;
}

// ---------------- launch ----------------
extern "C" void kernel_launch(void* const* d_in, const int* in_sizes, int n_in,
                              void* d_out, int out_size, void* d_ws, size_t ws_size,
                              hipStream_t stream) {
    const float* x      = (const float*)d_in[0];
    const float* A_log  = (const float*)d_in[1];
    const float* Dparam = (const float*)d_in[2];
    const float* W_dt1  = (const float*)d_in[3];
    const float* W_dt2  = (const float*)d_in[4];
    const float* b_dt   = (const float*)d_in[5];
    const float* W_B    = (const float*)d_in[6];
    const float* W_C    = (const float*)d_in[7];
    const float* conv_w = (const float*)d_in[8];
    const float* conv_b = (const float*)d_in[9];
    float* y = (float*)d_out;

    float* ws = (float*)d_ws;
    // layout (floats): xdtT 16M | bcT 256K | Wdt1T 64K | Wdt2T 64K | WBCT 32K
    float2* xdtT = (float2*)ws;
    float2* bcT  = (float2*)(ws + (size_t)2 * BB * LL * DD);
    float* Wdt1T = ws + (size_t)2 * BB * LL * DD + (size_t)2 * BB * LL * NN;
    float* Wdt2T = Wdt1T + 65536;
    float* WBCT  = Wdt2T + 65536;

    prep_kernel<<<256, 256, 0, stream>>>(W_dt1, W_dt2, W_B, W_C, Wdt1T, Wdt2T, WBCT);
    proj_kernel<<<BB * (LL / ROWS), 256, 0, stream>>>(x, conv_w, conv_b, Wdt1T, Wdt2T,
                                                      b_dt, WBCT, xdtT, bcT);
    scan_kernel<<<BB * KC * (DD / 4), 64, 0, stream>>>(xdtT, bcT, A_log, Dparam, y);
}